// Round 14
// baseline (311.258 us; speedup 1.0000x reference)
//
#include <hip/hip_runtime.h>

#define EPSF    1e-6f
#define BN_EPSF 1e-3f

typedef __attribute__((ext_vector_type(8))) short bf16x8;   // 8 bf16 in 4 VGPRs
typedef __attribute__((ext_vector_type(4))) float f32x4;

__device__ __forceinline__ unsigned short f2bf(float f) {
    unsigned int u = __builtin_bit_cast(unsigned int, f);
    u = (u + 0x7FFFu + ((u >> 16) & 1u)) >> 16;            // RNE
    return (unsigned short)u;
}
__device__ __forceinline__ float bf2f(unsigned short h) {
    unsigned int u = ((unsigned int)h) << 16;
    return __builtin_bit_cast(float, u);
}
__device__ __forceinline__ unsigned short f2h(float f) {
    return __builtin_bit_cast(unsigned short, (_Float16)f);
}
__device__ __forceinline__ float h2f(unsigned short h) {
    return (float)__builtin_bit_cast(_Float16, h);
}
// async global->LDS, 16 bytes per lane; lds dest is wave-uniform base + lane*16
__device__ __forceinline__ void gl16(const void* g, void* l) {
    __builtin_amdgcn_global_load_lds((const __attribute__((address_space(1))) void*)g,
                                     (__attribute__((address_space(3))) void*)l, 16, 0, 0);
}
// counted-vmcnt barrier pair
#define PIPE_WAIT(N)                                        \
    asm volatile("s_waitcnt vmcnt(" #N ")" ::: "memory");   \
    __builtin_amdgcn_sched_barrier(0);                      \
    __builtin_amdgcn_s_barrier();                           \
    __builtin_amdgcn_sched_barrier(0);

// ============ merged weight conversions (w2t | w3t | wt2 | wt1) ==============
// grid 3661: [0,288) w2t, [288,1440) w3t, [1440,2240) wt2, [2240,3661) wt1
__global__ __launch_bounds__(256) void k_wx(
        const float* __restrict__ w2, const float* __restrict__ w3,
        const float* __restrict__ cw2w, const float* __restrict__ W1,
        unsigned short* __restrict__ w2t, unsigned short* __restrict__ w3t,
        unsigned short* __restrict__ wt2, unsigned short* __restrict__ Wt) {
    __shared__ float tile[32][132];
    const int bid = blockIdx.x;
    if (bid < 288) {
        int idx = bid * 256 + threadIdx.x;                 // 73728
        int n = idx / 576, k = idx - n * 576;
        w2t[idx] = f2bf(w2[(size_t)k * 128 + n]);
    } else if (bid < 1440) {
        int idx = (bid - 288) * 256 + threadIdx.x;         // 294912
        int n = idx / 1152, k = idx - n * 1152;
        w3t[idx] = f2bf(w3[(size_t)k * 256 + n]);
    } else if (bid < 2240) {
        int idx = (bid - 1440) * 256 + threadIdx.x;        // 204800
        int n = idx / 3200, k = idx - n * 3200;
        wt2[idx] = f2bf(cw2w[(size_t)k * 64 + n]);
    } else {
        // Wt[n][k'], k'=s*928+q, zero for q>=900; coalesced LDS transpose
        const int idx = bid - 2240;                        // 0..1420
        const int s = idx / 29, q0 = (idx - s * 29) * 32;
        const int t = threadIdx.x;
        const int n = t & 127, rr = t >> 7;
        #pragma unroll
        for (int r = rr; r < 32; r += 2) {
            int q = q0 + r;
            tile[r][n] = (q < 900) ? W1[((size_t)(s * 900 + q)) * 128 + n] : 0.f;
        }
        __syncthreads();
        const int n2 = t >> 1, half = t & 1;
        unsigned short* dst = Wt + (size_t)n2 * 45472 + s * 928 + q0 + half * 16;
        #pragma unroll
        for (int u = 0; u < 16; ++u) dst[u] = f2bf(tile[half * 16 + u][n2]);
    }
}

// ======================= conv1 v3: LDS-staged strip, vector loads ============
__global__ __launch_bounds__(256) void k_conv1(
        const float* __restrict__ img,
        const float* __restrict__ w, const float* __restrict__ bias,
        unsigned short* __restrict__ c1) {
    __shared__ float lds[9][56];
    const int t = threadIdx.x;
    const int co = t & 63, wv = t >> 6;
    const int bx = blockIdx.x;                             // 15
    const int x0 = bx * 8;
    const int by = blockIdx.y;                             // 30
    const int b  = blockIdx.z;                             // 16
    if (t < 117) {
        const int r = t / 13, j = t - r * 13;
        const int iy = 8 * by + r;
        float4 v = make_float4(0.f, 0.f, 0.f, 0.f);
        const int fbase = 48 * bx + 4 * j;
        if (iy < 240 && fbase < 720)
            v = *(const float4*)(img + ((size_t)(b * 240 + iy)) * 720 + fbase);
        *(float4*)&lds[r][4 * j] = v;
    }
    __syncthreads();
    float wr[9][3];
    #pragma unroll
    for (int s = 0; s < 9; ++s)
        #pragma unroll
        for (int c = 0; c < 3; ++c)
            wr[s][c] = w[(s * 3 + c) * 64 + co];
    const float bb = bias[co];
    float acc[8] = {bb, bb, bb, bb, bb, bb, bb, bb};
    #pragma unroll
    for (int ky = 0; ky < 3; ++ky) {
        const int lrow = 2 * wv + ky;
        float iv[52];
        #pragma unroll
        for (int j = 0; j < 13; ++j) {
            float4 v = *(const float4*)&lds[lrow][4 * j];
            iv[4 * j] = v.x; iv[4 * j + 1] = v.y;
            iv[4 * j + 2] = v.z; iv[4 * j + 3] = v.w;
        }
        #pragma unroll
        for (int u = 0; u < 8; ++u)
            #pragma unroll
            for (int kx = 0; kx < 3; ++kx)
                #pragma unroll
                for (int c = 0; c < 3; ++c)
                    acc[u] = fmaf(iv[(2 * u + kx) * 3 + c], wr[ky * 3 + kx][c], acc[u]);
    }
    const int oy = by * 4 + wv;
    unsigned short* orow = c1 + ((size_t)(b * 121 + oy) * 121 + x0) * 64 + co;
    #pragma unroll
    for (int u = 0; u < 8; ++u)
        orow[(size_t)u * 64] = f2bf(fmaxf(acc[u], 0.f));
    if (x0 == 112)
        c1[((size_t)(b * 121 + oy) * 121 + 120) * 64 + co] = 0;
    if (oy == 119) {
        #pragma unroll
        for (int u = 0; u < 8; ++u)
            c1[((size_t)(b * 121 + 120) * 121 + x0 + u) * 64 + co] = 0;
        if (x0 == 112)
            c1[((size_t)(b * 121 + 120) * 121 + 120) * 64 + co] = 0;
    }
}

// ======================= conv2 MFMA: M=57600 N=128 K=576 (4-buf ring) ========
__global__ __launch_bounds__(256) void k_conv2(
        const unsigned short* __restrict__ c1, const unsigned short* __restrict__ w2t,
        const float* __restrict__ b2, unsigned short* __restrict__ c2) {
    __shared__ __align__(16) unsigned short As[4][128 * 32];
    __shared__ __align__(16) unsigned short Bs[4][128 * 32];
    const int t = threadIdx.x, w = t >> 6, l = t & 63;
    const int m0 = blockIdx.x * 128;                       // grid 450
    const int ko = (l & 3) * 8;
    size_t aga[2], bga[2];
    #pragma unroll
    for (int i = 0; i < 2; ++i) {
        int r = (w * 2 + i) * 16 + (l >> 2);
        int m = m0 + r;
        int bl = m / 3600, rem = m - bl * 3600, oy = rem / 60, ox = rem - oy * 60;
        aga[i] = (size_t)((bl * 121 + 2 * oy) * 121 + 2 * ox) * 64 + ko;
        bga[i] = (size_t)r * 576 + ko;
    }
    const int wr = (w >> 1) * 64, wc = (w & 1) * 64, lr = l & 15, lk = (l >> 4) * 8;
    f32x4 acc[4][4] = {};
    auto stage = [&](int s) {
        int buf = s & 3;
        int ky = s / 6, r6 = s - ky * 6, kx = r6 >> 1, h = r6 & 1;
        int aoff = (ky * 121 + kx) * 64 + h * 32;
        int boff = (ky * 3 + kx) * 64 + h * 32;
        #pragma unroll
        for (int i = 0; i < 2; ++i) {
            gl16(c1 + aga[i] + aoff, &As[buf][(w * 2 + i) * 512]);
            gl16(w2t + bga[i] + boff, &Bs[buf][(w * 2 + i) * 512]);
        }
    };
    stage(0); stage(1); stage(2);
    for (int s = 0; s < 18; ++s) {
        if (s + 2 < 18)      { PIPE_WAIT(8) }
        else if (s + 1 < 18) { PIPE_WAIT(4) }
        else                 { PIPE_WAIT(0) }
        if (s + 3 < 18) stage(s + 3);
        const int cur = s & 3;
        bf16x8 af[4], bfv[4];
        #pragma unroll
        for (int i = 0; i < 4; ++i) af[i] = *(const bf16x8*)&As[cur][(wr + i * 16 + lr) * 32 + lk];
        #pragma unroll
        for (int j = 0; j < 4; ++j) bfv[j] = *(const bf16x8*)&Bs[cur][(wc + j * 16 + lr) * 32 + lk];
        #pragma unroll
        for (int i = 0; i < 4; ++i)
            #pragma unroll
            for (int j = 0; j < 4; ++j)
                acc[i][j] = __builtin_amdgcn_mfma_f32_16x16x32_bf16(af[i], bfv[j], acc[i][j], 0, 0, 0);
    }
    float bias[4];
    #pragma unroll
    for (int j = 0; j < 4; ++j) bias[j] = b2[wc + j * 16 + lr];
    #pragma unroll
    for (int i = 0; i < 4; ++i)
        #pragma unroll
        for (int r = 0; r < 4; ++r) {
            int m = m0 + wr + i * 16 + (l >> 4) * 4 + r;
            int bl = m / 3600, rem = m - bl * 3600, oy = rem / 60, ox = rem - oy * 60;
            size_t ob = (size_t)((bl * 61 + oy) * 61 + ox) * 128;
            #pragma unroll
            for (int j = 0; j < 4; ++j)
                c2[ob + wc + j * 16 + lr] = f2bf(fmaxf(acc[i][j][r] + bias[j], 0.f));
            const bool bx = (ox == 59), by = (oy == 59);
            if (bx) {
                size_t zb = (size_t)((bl * 61 + oy) * 61 + 60) * 128;
                #pragma unroll
                for (int j = 0; j < 4; ++j) c2[zb + wc + j * 16 + lr] = 0;
            }
            if (by) {
                size_t zb = (size_t)((bl * 61 + 60) * 61 + ox) * 128;
                #pragma unroll
                for (int j = 0; j < 4; ++j) c2[zb + wc + j * 16 + lr] = 0;
            }
            if (bx && by) {
                size_t zb = (size_t)((bl * 61 + 60) * 61 + 60) * 128;
                #pragma unroll
                for (int j = 0; j < 4; ++j) c2[zb + wc + j * 16 + lr] = 0;
            }
        }
}

// ======================= conv3 MFMA: M=14400 N=256 K=1152 (4-buf ring) =======
// feat padded to [32][1024][256]
__global__ __launch_bounds__(256) void k_conv3(
        const unsigned short* __restrict__ c2, const unsigned short* __restrict__ w3t,
        const float* __restrict__ b3, unsigned short* __restrict__ feat, int f0) {
    __shared__ __align__(16) unsigned short As[4][128 * 32];
    __shared__ __align__(16) unsigned short Bs[4][64 * 32];
    const int t = threadIdx.x, w = t >> 6, l = t & 63;
    const int m0 = blockIdx.x * 128, n0 = blockIdx.y * 64;   // grid (113,4)
    const int ko = (l & 3) * 8;
    size_t aga[2], bga;
    #pragma unroll
    for (int i = 0; i < 2; ++i) {
        int r = (w * 2 + i) * 16 + (l >> 2);
        int m = min(m0 + r, 14399);
        int bl = m / 900, rem = m - bl * 900, oy = rem / 30, ox = rem - oy * 30;
        aga[i] = (size_t)((bl * 61 + 2 * oy) * 61 + 2 * ox) * 128 + ko;
    }
    { int n = n0 + w * 16 + (l >> 2); bga = (size_t)n * 1152 + ko; }
    const int wr = (w >> 1) * 64, wc = (w & 1) * 32, lr = l & 15, lk = (l >> 4) * 8;
    f32x4 acc[4][2] = {};
    auto stage = [&](int s) {
        int buf = s & 3;
        int ky = s / 12, r12 = s - ky * 12, kx = r12 >> 2, h = r12 & 3;
        int aoff = (ky * 61 + kx) * 128 + h * 32;
        int boff = (ky * 3 + kx) * 128 + h * 32;
        #pragma unroll
        for (int i = 0; i < 2; ++i)
            gl16(c2 + aga[i] + aoff, &As[buf][(w * 2 + i) * 512]);
        gl16(w3t + bga + boff, &Bs[buf][w * 512]);
    };
    stage(0); stage(1); stage(2);
    for (int s = 0; s < 36; ++s) {
        if (s + 2 < 36)      { PIPE_WAIT(6) }
        else if (s + 1 < 36) { PIPE_WAIT(3) }
        else                 { PIPE_WAIT(0) }
        if (s + 3 < 36) stage(s + 3);
        const int cur = s & 3;
        bf16x8 af[4], bfv[2];
        #pragma unroll
        for (int i = 0; i < 4; ++i) af[i] = *(const bf16x8*)&As[cur][(wr + i * 16 + lr) * 32 + lk];
        #pragma unroll
        for (int j = 0; j < 2; ++j) bfv[j] = *(const bf16x8*)&Bs[cur][(wc + j * 16 + lr) * 32 + lk];
        #pragma unroll
        for (int i = 0; i < 4; ++i)
            #pragma unroll
            for (int j = 0; j < 2; ++j)
                acc[i][j] = __builtin_amdgcn_mfma_f32_16x16x32_bf16(af[i], bfv[j], acc[i][j], 0, 0, 0);
    }
    float bias[2];
    #pragma unroll
    for (int j = 0; j < 2; ++j) bias[j] = b3[n0 + wc + j * 16 + lr];
    #pragma unroll
    for (int i = 0; i < 4; ++i)
        #pragma unroll
        for (int r = 0; r < 4; ++r) {
            int m = m0 + wr + i * 16 + (l >> 4) * 4 + r;
            if (m < 14400) {
                int bl = m / 900, pos = m - bl * 900;
                size_t ob = ((size_t)(f0 + bl) * 1024 + pos) * 256;
                #pragma unroll
                for (int j = 0; j < 2; ++j)
                    feat[ob + n0 + wc + j * 16 + lr] = f2bf(fmaxf(acc[i][j][r] + bias[j], 0.f));
            }
        }
}

// ======================= l2norm: wave per row, rows 900..1023 zeroed =========
__global__ __launch_bounds__(256) void k_l2norm(unsigned short* __restrict__ feat) {
    const int t = threadIdx.x, wv = t >> 6, ln = t & 63;
    const int R = blockIdx.x * 4 + wv;             // 32768 rows, grid 8192
    const int pos = R & 1023;
    ushort4* fp4 = (ushort4*)(feat + (size_t)R * 256);
    if (pos >= 900) { fp4[ln] = make_ushort4(0, 0, 0, 0); return; }
    ushort4 u = fp4[ln];
    float x0 = bf2f(u.x), x1 = bf2f(u.y), x2 = bf2f(u.z), x3 = bf2f(u.w);
    float s = x0 * x0 + x1 * x1 + x2 * x2 + x3 * x3;
    #pragma unroll
    for (int m = 1; m < 64; m <<= 1) s += __shfl_xor(s, m);
    const float inv = 1.f / sqrtf(s + EPSF);
    u.x = f2bf(x0 * inv); u.y = f2bf(x1 * inv);
    u.z = f2bf(x2 * inv); u.w = f2bf(x3 * inv);
    fp4[ln] = u;
}

// ======================= corr MFMA: per-b 1024x1024 padded, 128-tile =========
__global__ __launch_bounds__(256) void k_corr(
        const unsigned short* __restrict__ feat, unsigned short* __restrict__ corr) {
    __shared__ __align__(16) unsigned short As[4][128 * 32];
    __shared__ __align__(16) unsigned short Bs[4][128 * 32];
    const int t = threadIdx.x, w = t >> 6, l = t & 63;
    const int id0 = blockIdx.x;                            // 1024
    const int sw = (id0 & 7) * 128 + (id0 >> 3);           // bijective XCD swizzle
    const int b = sw >> 6, rem = sw & 63;
    const int p0 = (rem >> 3) * 128, q0 = (rem & 7) * 128;
    const int ko = (l & 3) * 8;
    const unsigned short* fA = feat + (size_t)b * 1024 * 256;
    const unsigned short* fB = feat + (size_t)(16 + b) * 1024 * 256;
    size_t aga[2], bga[2];
    #pragma unroll
    for (int i = 0; i < 2; ++i) {
        int r = (w * 2 + i) * 16 + (l >> 2);
        aga[i] = (size_t)(p0 + r) * 256 + ko;
        bga[i] = (size_t)(q0 + r) * 256 + ko;
    }
    const int wr = (w >> 1) * 64, wc = (w & 1) * 64, lr = l & 15, lk = (l >> 4) * 8;
    f32x4 acc[4][4] = {};
    auto stage = [&](int s) {
        int buf = s & 3;
        #pragma unroll
        for (int i = 0; i < 2; ++i) {
            gl16(fA + aga[i] + s * 32, &As[buf][(w * 2 + i) * 512]);
            gl16(fB + bga[i] + s * 32, &Bs[buf][(w * 2 + i) * 512]);
        }
    };
    stage(0); stage(1); stage(2);
    for (int s = 0; s < 8; ++s) {
        if (s + 2 < 8)      { PIPE_WAIT(8) }
        else if (s + 1 < 8) { PIPE_WAIT(4) }
        else                { PIPE_WAIT(0) }
        if (s + 3 < 8) stage(s + 3);
        const int cur = s & 3;
        bf16x8 af[4], bfv[4];
        #pragma unroll
        for (int i = 0; i < 4; ++i) af[i] = *(const bf16x8*)&As[cur][(wr + i * 16 + lr) * 32 + lk];
        #pragma unroll
        for (int j = 0; j < 4; ++j) bfv[j] = *(const bf16x8*)&Bs[cur][(wc + j * 16 + lr) * 32 + lk];
        #pragma unroll
        for (int i = 0; i < 4; ++i)
            #pragma unroll
            for (int j = 0; j < 4; ++j)
                acc[i][j] = __builtin_amdgcn_mfma_f32_16x16x32_bf16(af[i], bfv[j], acc[i][j], 0, 0, 0);
    }
    unsigned short* cb = corr + (size_t)b * 960 * 960;
    #pragma unroll
    for (int i = 0; i < 4; ++i)
        #pragma unroll
        for (int r = 0; r < 4; ++r) {
            int row = p0 + wr + i * 16 + (l >> 4) * 4 + r;
            if (row < 960) {
                #pragma unroll
                for (int j = 0; j < 4; ++j) {
                    int col = q0 + wc + j * 16 + lr;
                    if (col < 960)
                        cb[(size_t)row * 960 + col] = f2bf(fmaxf(acc[i][j][r], 0.f));
                }
            }
        }
}

// ======================= corr L2 norm: one wave per row ======================
__global__ __launch_bounds__(256) void k_corrnorm(unsigned short* __restrict__ corr) {
    const int t = threadIdx.x, wv = t >> 6, ln = t & 63;
    const int row = blockIdx.x * 4 + wv;       // 14400 rows, grid 3600
    const int b = row / 900, p = row - b * 900;
    ushort4* cp4 = (ushort4*)(corr + ((size_t)b * 960 + p) * 960);
    float x[16];
    float s = 0.f;
    #pragma unroll
    for (int i = 0; i < 4; ++i) {
        const int idx = ln + 64 * i;
        float v0 = 0.f, v1 = 0.f, v2 = 0.f, v3 = 0.f;
        if (idx < 225) {
            ushort4 u = cp4[idx];
            v0 = fmaxf(bf2f(u.x), 0.f); v1 = fmaxf(bf2f(u.y), 0.f);
            v2 = fmaxf(bf2f(u.z), 0.f); v3 = fmaxf(bf2f(u.w), 0.f);
        }
        x[i * 4 + 0] = v0; x[i * 4 + 1] = v1; x[i * 4 + 2] = v2; x[i * 4 + 3] = v3;
        s += v0 * v0 + v1 * v1 + v2 * v2 + v3 * v3;
    }
    #pragma unroll
    for (int m = 1; m < 64; m <<= 1) s += __shfl_xor(s, m);
    const float sc = 1.f / sqrtf(s + EPSF);
    #pragma unroll
    for (int i = 0; i < 4; ++i) {
        const int idx = ln + 64 * i;
        if (idx < 225) {
            ushort4 u;
            u.x = f2bf(x[i * 4 + 0] * sc); u.y = f2bf(x[i * 4 + 1] * sc);
            u.z = f2bf(x[i * 4 + 2] * sc); u.w = f2bf(x[i * 4 + 3] * sc);
            cp4[idx] = u;
        }
    }
}

// ======================= cw1 MFMA v8: 256x128 block, 2 blocks/CU co-resident =
// M=9216 N=128; 4 waves of 64x128; BK=32/phase; 3-seg ring (72 KB); T2 swizzle;
// single barrier/phase; vmcnt(6). grid 504 = 36mt x 14ks -> ~2 blocks/CU so two
// independent barrier domains overlap LDS-read and MFMA sections across blocks.
__global__ __launch_bounds__(256, 2) void k_cw1(
        const unsigned short* __restrict__ corr, const unsigned short* __restrict__ Wt,
        unsigned short* __restrict__ part) {
    __shared__ __align__(16) unsigned short As[3 * 256 * 32];   // 48 KB
    __shared__ __align__(16) unsigned short Bs[3 * 128 * 32];   // 24 KB
    const int t = threadIdx.x, w = t >> 6, l = t & 63;
    const int bid = blockIdx.x;                            // 504
    const int mt = bid % 36, ks = bid / 36;
    const int m0 = mt * 256;
    // staging: row = t>>2, phys chunk = t&3; fetch global chunk = (t&3)^((row>>1)&3)
    const int kswz = ((t & 3) ^ ((t >> 3) & 3)) * 8;
    size_t aga[4];
    #pragma unroll
    for (int i = 0; i < 4; ++i) {
        int r = i * 64 + (t >> 2);
        int m = m0 + r;
        int b = m / 576, rem = m - b * 576, oy = rem / 24, ox = rem - oy * 24;
        aga[i] = (size_t)(b * 960 + oy * 30 + ox) * 960 + kswz;
    }
    size_t bga[2];
    #pragma unroll
    for (int j = 0; j < 2; ++j)
        bga[j] = (size_t)(j * 64 + (t >> 2)) * 45472 + kswz;
    // q-major K schedule: 1421 steps of 32; ks<7 get 102, else 101
    const int sbase = ks * 101 + min(ks, 7);
    const int nt = 101 + (ks < 7 ? 1 : 0);
    const int wm = w * 64;
    const int lr = l & 15, cI = l >> 4;
    const int rsw = (cI ^ ((lr >> 1) & 3)) * 8;     // swizzled read chunk (elems)
    f32x4 acc[4][8] = {};
    auto stage = [&](int sidx) {
        const int seg = sidx % 3;
        const int s = sbase + sidx;
        const int qi = s / 49, sq = s - qi * 49;
        const int ky = sq / 7, kx = sq - ky * 7;
        const int aoff = (ky * 30 + kx) * 960 + qi * 32;
        const int boff = sq * 928 + qi * 32;
        #pragma unroll
        for (int i = 0; i < 4; ++i)
            gl16(corr + aga[i] + aoff, &As[seg * 8192 + i * 2048 + w * 512]);
        #pragma unroll
        for (int j = 0; j < 2; ++j)
            gl16(Wt + bga[j] + boff, &Bs[seg * 4096 + j * 2048 + w * 512]);
    };
    stage(0); stage(1);
    for (int s = 0; s < nt; ++s) {
        if (s + 1 < nt) {
            asm volatile("s_waitcnt vmcnt(6)" ::: "memory");
        } else {
            asm volatile("s_waitcnt vmcnt(0)" ::: "memory");
        }
        __builtin_amdgcn_sched_barrier(0);
        __builtin_amdgcn_s_barrier();
        __builtin_amdgcn_sched_barrier(0);
        const int seg = s % 3;
        bf16x8 af[4], bfv[8];
        #pragma unroll
        for (int i = 0; i < 4; ++i)
            af[i] = *(const bf16x8*)&As[seg * 8192 + (wm + i * 16 + lr) * 32 + rsw];
        #pragma unroll
        for (int j = 0; j < 8; ++j)
            bfv[j] = *(const bf16x8*)&Bs[seg * 4096 + (j * 16 + lr) * 32 + rsw];
        if (s + 2 < nt) stage(s + 2);
        asm volatile("s_waitcnt lgkmcnt(0)" ::: "memory");
        __builtin_amdgcn_sched_barrier(0);
        __builtin_amdgcn_s_setprio(1);
        #pragma unroll
        for (int i = 0; i < 4; ++i)
            #pragma unroll
            for (int j = 0; j < 8; ++j)
                acc[i][j] = __builtin_amdgcn_mfma_f32_16x16x32_bf16(af[i], bfv[j], acc[i][j], 0, 0, 0);
        __builtin_amdgcn_s_setprio(0);
        __builtin_amdgcn_sched_barrier(0);
        // single rendezvous per phase; ring distance 2 keeps WAR safe (see hdr)
    }
    unsigned short* pb = part + ((size_t)ks * 9216 + m0) * 128;
    #pragma unroll
    for (int i = 0; i < 4; ++i)
        #pragma unroll
        for (int r = 0; r < 4; ++r) {
            int row = wm + i * 16 + cI * 4 + r;
            #pragma unroll
            for (int j = 0; j < 8; ++j)
                pb[(size_t)row * 128 + j * 16 + lr] = f2h(acc[i][j][r]);
        }
}

// ======================= reduce 14 fp16 partials + bias + relu + BN -> bf16 ==
__global__ __launch_bounds__(256) void k_r1fin(
        const unsigned short* __restrict__ part, const float* __restrict__ cb1,
        const float* __restrict__ g1, const float* __restrict__ be1,
        const float* __restrict__ m1, const float* __restrict__ v1,
        unsigned short* __restrict__ r1) {
    const int idx = blockIdx.x * 256 + threadIdx.x;        // grid 1152
    const size_t base = (size_t)idx * 4;
    const size_t N = 9216 * 128;
    float s0 = 0.f, s1 = 0.f, s2 = 0.f, s3 = 0.f;
    #pragma unroll
    for (int i = 0; i < 14; ++i) {
        ushort4 u = *(const ushort4*)(part + i * N + base);
        s0 += h2f(u.x); s1 += h2f(u.y); s2 += h2f(u.z); s3 += h2f(u.w);
    }
    const int co = (int)(base & 127);
    float r[4] = {s0, s1, s2, s3};
    ushort4 o;
    unsigned short* op = (unsigned short*)&o;
    #pragma unroll
    for (int j = 0; j < 4; ++j) {
        int c = co + j;
        float x = fmaxf(r[j] + cb1[c], 0.f);
        x = (x - m1[c]) * (g1[c] / sqrtf(v1[c] + BN_EPSF)) + be1[c];
        op[j] = f2bf(x);
    }
    *(ushort4*)(r1 + base) = o;
}

// ======================= cw2 MFMA: M=6400 N=64 K=3200, K-split 4, 4-buf ======
__global__ __launch_bounds__(256) void k_cw2(
        const unsigned short* __restrict__ r1, const unsigned short* __restrict__ Wt2,
        float* __restrict__ partC) {
    __shared__ __align__(16) unsigned short As[4][64 * 32];
    __shared__ __align__(16) unsigned short Bs[4][64 * 32];
    const int t = threadIdx.x, w = t >> 6, l = t & 63;
    const int bid = blockIdx.x;                            // 400
    const int mtb = bid % 100, ks = bid / 100;
    const int m0 = mtb * 64;
    const int sbase = ks * 25;
    const int ko = (l & 3) * 8;
    const int wi = w & 1;
    size_t ga[2];
    #pragma unroll
    for (int i = 0; i < 2; ++i) {
        int r = (wi * 2 + i) * 16 + (l >> 2);
        if (w < 2) {
            int m = m0 + r;
            int b = m / 400, rem = m - b * 400, oy = rem / 20, ox = rem - oy * 20;
            ga[i] = (size_t)((b * 24 + oy) * 24 + ox) * 128 + ko;
        } else {
            ga[i] = (size_t)r * 3200 + ko;
        }
    }
    const int wr = (w >> 1) * 32, wc = (w & 1) * 32, lr = l & 15, lk = (l >> 4) * 8;
    f32x4 acc[2][2] = {};
    auto stage = [&](int sidx) {
        int buf = sidx & 3;
        int s = sbase + sidx;
        int kyx = s >> 2, h = s & 3;
        int ky = kyx / 5, kx = kyx - ky * 5;
        int aoff = (ky * 24 + kx) * 128 + h * 32;
        int boff = s * 32;
        #pragma unroll
        for (int i = 0; i < 2; ++i) {
            unsigned short* dst = (w < 2) ? &As[buf][(wi * 2 + i) * 512]
                                          : &Bs[buf][(wi * 2 + i) * 512];
            const unsigned short* src = (w < 2) ? r1 + ga[i] + aoff : Wt2 + ga[i] + boff;
            gl16(src, dst);
        }
    };
    stage(0); stage(1); stage(2);
    for (int s = 0; s < 25; ++s) {
        if (s + 2 < 25)      { PIPE_WAIT(4) }
        else if (s + 1 < 25) { PIPE_WAIT(2) }
        else                 { PIPE_WAIT(0) }
        if (s + 3 < 25) stage(s + 3);
        const int cur = s & 3;
        bf16x8 af[2], bfv[2];
        #pragma unroll
        for (int i = 0; i < 2; ++i) af[i] = *(const bf16x8*)&As[cur][(wr + i * 16 + lr) * 32 + lk];
        #pragma unroll
        for (int j = 0; j < 2; ++j) bfv[j] = *(const bf16x8*)&Bs[cur][(wc + j * 16 + lr) * 32 + lk];
        #pragma unroll
        for (int i = 0; i < 2; ++i)
            #pragma unroll
            for (int j = 0; j < 2; ++j)
                acc[i][j] = __builtin_amdgcn_mfma_f32_16x16x32_bf16(af[i], bfv[j], acc[i][j], 0, 0, 0);
    }
    float* pc = partC + (size_t)ks * 409600;
    #pragma unroll
    for (int i = 0; i < 2; ++i)
        #pragma unroll
        for (int r = 0; r < 4; ++r) {
            int m = m0 + wr + i * 16 + (l >> 4) * 4 + r;
            #pragma unroll
            for (int j = 0; j < 2; ++j)
                pc[(size_t)m * 64 + wc + j * 16 + lr] = acc[i][j][r];
        }
}

// ======================= dense: fold cw2 finalize (bias/relu/BN) + matvec ====
__global__ __launch_bounds__(256) void k_dense(
        const float* __restrict__ partC, const float* __restrict__ cb2,
        const float* __restrict__ g2, const float* __restrict__ be2,
        const float* __restrict__ m2, const float* __restrict__ v2,
        const float* __restrict__ dw, float* __restrict__ partD) {
    const int b = blockIdx.x, kb = blockIdx.y, t = threadIdx.x;  // (16,5)
    const int co = t & 63;
    const float sc2 = g2[co] / sqrtf(v2[co] + BN_EPSF);
    const float sh2 = be2[co] - m2[co] * sc2;
    const float bb = cb2[co];
    float s[18] = {};
    for (int k = t; k < 5120; k += 256) {
        const int kk = kb * 5120 + k;
        const size_t pi = (size_t)(b * 400 + (kk >> 6)) * 64 + co;
        float p = partC[pi] + partC[pi + 409600] + partC[pi + 819200] + partC[pi + 1228800];
        p = fmaxf(p + bb, 0.f) * sc2 + sh2;
        const float* dr = dw + (size_t)kk * 18;
        #pragma unroll
        for (int j = 0; j < 18; ++j) s[j] = fmaf(p, dr[j], s[j]);
    }
    #pragma unroll
    for (int j = 0; j < 18; ++j)
        #pragma unroll
        for (int m = 1; m < 64; m <<= 1) s[j] += __shfl_xor(s[j], m);
    __shared__ float red[4][18];
    if ((t & 63) == 0) {
        #pragma unroll
        for (int j = 0; j < 18; ++j) red[t >> 6][j] = s[j];
    }
    __syncthreads();
    if (t < 18) partD[(b * 5 + kb) * 18 + t] = red[0][t] + red[1][t] + red[2][t] + red[3][t];
}
__global__ __launch_bounds__(288) void k_dfin(
        const float* __restrict__ partD, const float* __restrict__ db,
        float* __restrict__ out) {
    const int i = threadIdx.x;                 // 288
    const int b = i / 18, j = i - b * 18;
    float s = db[j];
    #pragma unroll
    for (int k = 0; k < 5; ++k) s += partD[(b * 5 + k) * 18 + j];
    out[i] = s;
}

extern "C" void kernel_launch(void* const* d_in, const int* in_sizes, int n_in,
                              void* d_out, int out_size, void* d_ws, size_t ws_size,
                              hipStream_t stream) {
    const float* imgA = (const float*)d_in[0];
    const float* imgB = (const float*)d_in[1];
    const float* w1  = (const float*)d_in[2];
    const float* b1  = (const float*)d_in[3];
    const float* w2  = (const float*)d_in[4];
    const float* b2  = (const float*)d_in[5];
    const float* w3  = (const float*)d_in[6];
    const float* b3  = (const float*)d_in[7];
    const float* cw1 = (const float*)d_in[8];
    const float* cb1 = (const float*)d_in[9];
    const float* g1  = (const float*)d_in[10];
    const float* be1 = (const float*)d_in[11];
    const float* m1  = (const float*)d_in[12];
    const float* v1  = (const float*)d_in[13];
    const float* cw2 = (const float*)d_in[14];
    const float* cb2 = (const float*)d_in[15];
    const float* g2  = (const float*)d_in[16];
    const float* be2 = (const float*)d_in[17];
    const float* m2  = (const float*)d_in[18];
    const float* v2  = (const float*)d_in[19];
    const float* dw  = (const float*)d_in[20];
    const float* db  = (const float*)d_in[21];

    // ws layout (bytes), max end = 77,150,208:
    //  persistent : Wt@62,740,480 (11.64MB, written by k_wx up front)
    //  conv phase : c1@0 (30.0MB) c2@29,984,768 (15.2MB) w2t@45,225,984
    //               w3t@45,373,440  feat@45,963,264 (16.8MB, [32][1024][256])
    //  corr phase : corr@0 (29.5MB, c1 dead)
    //  cw1 phase  : part@29,491,200 (33.0MB fp16 x14; feat/c2/w2t/w3t dead;
    //               ends 62,521,344 < Wt)
    //  tail       : r1@74,381,312 (2.36MB)  Wt2@76,740,608 (0.41MB)
    //               partC@0 (6.55MB, corr dead)  partD@6,553,600
    char* ws = (char*)d_ws;
    unsigned short* c1   = (unsigned short*)(ws + 0);
    unsigned short* c2   = (unsigned short*)(ws + 29984768);
    unsigned short* w2t  = (unsigned short*)(ws + 45225984);
    unsigned short* w3t  = (unsigned short*)(ws + 45373440);
    unsigned short* feat = (unsigned short*)(ws + 45963264);
    unsigned short* Wt   = (unsigned short*)(ws + 62740480);
    unsigned short* corr = (unsigned short*)(ws + 0);
    unsigned short* part = (unsigned short*)(ws + 29491200);
    unsigned short* r1   = (unsigned short*)(ws + 74381312);
    unsigned short* Wt2  = (unsigned short*)(ws + 76740608);
    float*          partC= (float*)(ws + 0);
    float*          partD= (float*)(ws + 6553600);

    k_wx<<<dim3(3661), 256, 0, stream>>>(w2, w3, cw2, cw1, w2t, w3t, Wt2, Wt);

    for (int chunk = 0; chunk < 2; ++chunk) {
        const float* img = chunk ? imgB : imgA;
        const int f0 = chunk * 16;
        k_conv1<<<dim3(15, 30, 16), 256, 0, stream>>>(img, w1, b1, c1);
        k_conv2<<<dim3(450),        256, 0, stream>>>(c1, w2t, b2, c2);
        k_conv3<<<dim3(113, 4),     256, 0, stream>>>(c2, w3t, b3, feat, f0);
    }
    k_l2norm  <<<dim3(8192),  256, 0, stream>>>(feat);
    k_corr    <<<dim3(1024),  256, 0, stream>>>(feat, corr);
    k_corrnorm<<<dim3(3600),  256, 0, stream>>>(corr);
    k_cw1     <<<dim3(504),   256, 0, stream>>>(corr, Wt, part);
    k_r1fin   <<<dim3(1152),  256, 0, stream>>>(part, cb1, g1, be1, m1, v1, r1);
    k_cw2     <<<dim3(400),   256, 0, stream>>>(r1, Wt2, partC);
    k_dense   <<<dim3(16, 5), 256, 0, stream>>>(partC, cb2, g2, be2, m2, v2, dw, partD);
    k_dfin    <<<dim3(1),     288, 0, stream>>>(partD, db, (float*)d_out);
}

// Round 15
// 296.990 us; speedup vs baseline: 1.0480x; 1.0480x over previous
//
#include <hip/hip_runtime.h>

#define EPSF    1e-6f
#define BN_EPSF 1e-3f

typedef __attribute__((ext_vector_type(8))) short bf16x8;   // 8 bf16 in 4 VGPRs
typedef __attribute__((ext_vector_type(4))) float f32x4;

__device__ __forceinline__ unsigned short f2bf(float f) {
    unsigned int u = __builtin_bit_cast(unsigned int, f);
    u = (u + 0x7FFFu + ((u >> 16) & 1u)) >> 16;            // RNE
    return (unsigned short)u;
}
__device__ __forceinline__ float bf2f(unsigned short h) {
    unsigned int u = ((unsigned int)h) << 16;
    return __builtin_bit_cast(float, u);
}
__device__ __forceinline__ unsigned short f2h(float f) {
    return __builtin_bit_cast(unsigned short, (_Float16)f);
}
__device__ __forceinline__ float h2f(unsigned short h) {
    return (float)__builtin_bit_cast(_Float16, h);
}
// async global->LDS, 16 bytes per lane; lds dest is wave-uniform base + lane*16
__device__ __forceinline__ void gl16(const void* g, void* l) {
    __builtin_amdgcn_global_load_lds((const __attribute__((address_space(1))) void*)g,
                                     (__attribute__((address_space(3))) void*)l, 16, 0, 0);
}
// counted-vmcnt barrier pair
#define PIPE_WAIT(N)                                        \
    asm volatile("s_waitcnt vmcnt(" #N ")" ::: "memory");   \
    __builtin_amdgcn_sched_barrier(0);                      \
    __builtin_amdgcn_s_barrier();                           \
    __builtin_amdgcn_sched_barrier(0);

// ============ merged weight conversions (w2t | w3t | wt2 | wt1) ==============
// grid 3661: [0,288) w2t, [288,1440) w3t, [1440,2240) wt2, [2240,3661) wt1
__global__ __launch_bounds__(256) void k_wx(
        const float* __restrict__ w2, const float* __restrict__ w3,
        const float* __restrict__ cw2w, const float* __restrict__ W1,
        unsigned short* __restrict__ w2t, unsigned short* __restrict__ w3t,
        unsigned short* __restrict__ wt2, unsigned short* __restrict__ Wt) {
    __shared__ float tile[32][132];
    const int bid = blockIdx.x;
    if (bid < 288) {
        int idx = bid * 256 + threadIdx.x;                 // 73728
        int n = idx / 576, k = idx - n * 576;
        w2t[idx] = f2bf(w2[(size_t)k * 128 + n]);
    } else if (bid < 1440) {
        int idx = (bid - 288) * 256 + threadIdx.x;         // 294912
        int n = idx / 1152, k = idx - n * 1152;
        w3t[idx] = f2bf(w3[(size_t)k * 256 + n]);
    } else if (bid < 2240) {
        int idx = (bid - 1440) * 256 + threadIdx.x;        // 204800
        int n = idx / 3200, k = idx - n * 3200;
        wt2[idx] = f2bf(cw2w[(size_t)k * 64 + n]);
    } else {
        // Wt[n][k'], k'=s*928+q, zero for q>=900; coalesced LDS transpose
        const int idx = bid - 2240;                        // 0..1420
        const int s = idx / 29, q0 = (idx - s * 29) * 32;
        const int t = threadIdx.x;
        const int n = t & 127, rr = t >> 7;
        #pragma unroll
        for (int r = rr; r < 32; r += 2) {
            int q = q0 + r;
            tile[r][n] = (q < 900) ? W1[((size_t)(s * 900 + q)) * 128 + n] : 0.f;
        }
        __syncthreads();
        const int n2 = t >> 1, half = t & 1;
        unsigned short* dst = Wt + (size_t)n2 * 45472 + s * 928 + q0 + half * 16;
        #pragma unroll
        for (int u = 0; u < 16; ++u) dst[u] = f2bf(tile[half * 16 + u][n2]);
    }
}

// ======================= conv1 v3: LDS-staged strip, vector loads ============
__global__ __launch_bounds__(256) void k_conv1(
        const float* __restrict__ img,
        const float* __restrict__ w, const float* __restrict__ bias,
        unsigned short* __restrict__ c1) {
    __shared__ float lds[9][56];
    const int t = threadIdx.x;
    const int co = t & 63, wv = t >> 6;
    const int bx = blockIdx.x;                             // 15
    const int x0 = bx * 8;
    const int by = blockIdx.y;                             // 30
    const int b  = blockIdx.z;                             // 16
    if (t < 117) {
        const int r = t / 13, j = t - r * 13;
        const int iy = 8 * by + r;
        float4 v = make_float4(0.f, 0.f, 0.f, 0.f);
        const int fbase = 48 * bx + 4 * j;
        if (iy < 240 && fbase < 720)
            v = *(const float4*)(img + ((size_t)(b * 240 + iy)) * 720 + fbase);
        *(float4*)&lds[r][4 * j] = v;
    }
    __syncthreads();
    float wr[9][3];
    #pragma unroll
    for (int s = 0; s < 9; ++s)
        #pragma unroll
        for (int c = 0; c < 3; ++c)
            wr[s][c] = w[(s * 3 + c) * 64 + co];
    const float bb = bias[co];
    float acc[8] = {bb, bb, bb, bb, bb, bb, bb, bb};
    #pragma unroll
    for (int ky = 0; ky < 3; ++ky) {
        const int lrow = 2 * wv + ky;
        float iv[52];
        #pragma unroll
        for (int j = 0; j < 13; ++j) {
            float4 v = *(const float4*)&lds[lrow][4 * j];
            iv[4 * j] = v.x; iv[4 * j + 1] = v.y;
            iv[4 * j + 2] = v.z; iv[4 * j + 3] = v.w;
        }
        #pragma unroll
        for (int u = 0; u < 8; ++u)
            #pragma unroll
            for (int kx = 0; kx < 3; ++kx)
                #pragma unroll
                for (int c = 0; c < 3; ++c)
                    acc[u] = fmaf(iv[(2 * u + kx) * 3 + c], wr[ky * 3 + kx][c], acc[u]);
    }
    const int oy = by * 4 + wv;
    unsigned short* orow = c1 + ((size_t)(b * 121 + oy) * 121 + x0) * 64 + co;
    #pragma unroll
    for (int u = 0; u < 8; ++u)
        orow[(size_t)u * 64] = f2bf(fmaxf(acc[u], 0.f));
    if (x0 == 112)
        c1[((size_t)(b * 121 + oy) * 121 + 120) * 64 + co] = 0;
    if (oy == 119) {
        #pragma unroll
        for (int u = 0; u < 8; ++u)
            c1[((size_t)(b * 121 + 120) * 121 + x0 + u) * 64 + co] = 0;
        if (x0 == 112)
            c1[((size_t)(b * 121 + 120) * 121 + 120) * 64 + co] = 0;
    }
}

// ======================= conv2 MFMA: M=57600 N=128 K=576 (4-buf ring) ========
__global__ __launch_bounds__(256) void k_conv2(
        const unsigned short* __restrict__ c1, const unsigned short* __restrict__ w2t,
        const float* __restrict__ b2, unsigned short* __restrict__ c2) {
    __shared__ __align__(16) unsigned short As[4][128 * 32];
    __shared__ __align__(16) unsigned short Bs[4][128 * 32];
    const int t = threadIdx.x, w = t >> 6, l = t & 63;
    const int m0 = blockIdx.x * 128;                       // grid 450
    const int ko = (l & 3) * 8;
    size_t aga[2], bga[2];
    #pragma unroll
    for (int i = 0; i < 2; ++i) {
        int r = (w * 2 + i) * 16 + (l >> 2);
        int m = m0 + r;
        int bl = m / 3600, rem = m - bl * 3600, oy = rem / 60, ox = rem - oy * 60;
        aga[i] = (size_t)((bl * 121 + 2 * oy) * 121 + 2 * ox) * 64 + ko;
        bga[i] = (size_t)r * 576 + ko;
    }
    const int wr = (w >> 1) * 64, wc = (w & 1) * 64, lr = l & 15, lk = (l >> 4) * 8;
    f32x4 acc[4][4] = {};
    auto stage = [&](int s) {
        int buf = s & 3;
        int ky = s / 6, r6 = s - ky * 6, kx = r6 >> 1, h = r6 & 1;
        int aoff = (ky * 121 + kx) * 64 + h * 32;
        int boff = (ky * 3 + kx) * 64 + h * 32;
        #pragma unroll
        for (int i = 0; i < 2; ++i) {
            gl16(c1 + aga[i] + aoff, &As[buf][(w * 2 + i) * 512]);
            gl16(w2t + bga[i] + boff, &Bs[buf][(w * 2 + i) * 512]);
        }
    };
    stage(0); stage(1); stage(2);
    for (int s = 0; s < 18; ++s) {
        if (s + 2 < 18)      { PIPE_WAIT(8) }
        else if (s + 1 < 18) { PIPE_WAIT(4) }
        else                 { PIPE_WAIT(0) }
        if (s + 3 < 18) stage(s + 3);
        const int cur = s & 3;
        bf16x8 af[4], bfv[4];
        #pragma unroll
        for (int i = 0; i < 4; ++i) af[i] = *(const bf16x8*)&As[cur][(wr + i * 16 + lr) * 32 + lk];
        #pragma unroll
        for (int j = 0; j < 4; ++j) bfv[j] = *(const bf16x8*)&Bs[cur][(wc + j * 16 + lr) * 32 + lk];
        #pragma unroll
        for (int i = 0; i < 4; ++i)
            #pragma unroll
            for (int j = 0; j < 4; ++j)
                acc[i][j] = __builtin_amdgcn_mfma_f32_16x16x32_bf16(af[i], bfv[j], acc[i][j], 0, 0, 0);
    }
    float bias[4];
    #pragma unroll
    for (int j = 0; j < 4; ++j) bias[j] = b2[wc + j * 16 + lr];
    #pragma unroll
    for (int i = 0; i < 4; ++i)
        #pragma unroll
        for (int r = 0; r < 4; ++r) {
            int m = m0 + wr + i * 16 + (l >> 4) * 4 + r;
            int bl = m / 3600, rem = m - bl * 3600, oy = rem / 60, ox = rem - oy * 60;
            size_t ob = (size_t)((bl * 61 + oy) * 61 + ox) * 128;
            #pragma unroll
            for (int j = 0; j < 4; ++j)
                c2[ob + wc + j * 16 + lr] = f2bf(fmaxf(acc[i][j][r] + bias[j], 0.f));
            const bool bx = (ox == 59), by = (oy == 59);
            if (bx) {
                size_t zb = (size_t)((bl * 61 + oy) * 61 + 60) * 128;
                #pragma unroll
                for (int j = 0; j < 4; ++j) c2[zb + wc + j * 16 + lr] = 0;
            }
            if (by) {
                size_t zb = (size_t)((bl * 61 + 60) * 61 + ox) * 128;
                #pragma unroll
                for (int j = 0; j < 4; ++j) c2[zb + wc + j * 16 + lr] = 0;
            }
            if (bx && by) {
                size_t zb = (size_t)((bl * 61 + 60) * 61 + 60) * 128;
                #pragma unroll
                for (int j = 0; j < 4; ++j) c2[zb + wc + j * 16 + lr] = 0;
            }
        }
}

// ======================= conv3 MFMA: M=14400 N=256 K=1152 (4-buf ring) =======
// feat padded to [32][1024][256]
__global__ __launch_bounds__(256) void k_conv3(
        const unsigned short* __restrict__ c2, const unsigned short* __restrict__ w3t,
        const float* __restrict__ b3, unsigned short* __restrict__ feat, int f0) {
    __shared__ __align__(16) unsigned short As[4][128 * 32];
    __shared__ __align__(16) unsigned short Bs[4][64 * 32];
    const int t = threadIdx.x, w = t >> 6, l = t & 63;
    const int m0 = blockIdx.x * 128, n0 = blockIdx.y * 64;   // grid (113,4)
    const int ko = (l & 3) * 8;
    size_t aga[2], bga;
    #pragma unroll
    for (int i = 0; i < 2; ++i) {
        int r = (w * 2 + i) * 16 + (l >> 2);
        int m = min(m0 + r, 14399);
        int bl = m / 900, rem = m - bl * 900, oy = rem / 30, ox = rem - oy * 30;
        aga[i] = (size_t)((bl * 61 + 2 * oy) * 61 + 2 * ox) * 128 + ko;
    }
    { int n = n0 + w * 16 + (l >> 2); bga = (size_t)n * 1152 + ko; }
    const int wr = (w >> 1) * 64, wc = (w & 1) * 32, lr = l & 15, lk = (l >> 4) * 8;
    f32x4 acc[4][2] = {};
    auto stage = [&](int s) {
        int buf = s & 3;
        int ky = s / 12, r12 = s - ky * 12, kx = r12 >> 2, h = r12 & 3;
        int aoff = (ky * 61 + kx) * 128 + h * 32;
        int boff = (ky * 3 + kx) * 128 + h * 32;
        #pragma unroll
        for (int i = 0; i < 2; ++i)
            gl16(c2 + aga[i] + aoff, &As[buf][(w * 2 + i) * 512]);
        gl16(w3t + bga + boff, &Bs[buf][w * 512]);
    };
    stage(0); stage(1); stage(2);
    for (int s = 0; s < 36; ++s) {
        if (s + 2 < 36)      { PIPE_WAIT(6) }
        else if (s + 1 < 36) { PIPE_WAIT(3) }
        else                 { PIPE_WAIT(0) }
        if (s + 3 < 36) stage(s + 3);
        const int cur = s & 3;
        bf16x8 af[4], bfv[2];
        #pragma unroll
        for (int i = 0; i < 4; ++i) af[i] = *(const bf16x8*)&As[cur][(wr + i * 16 + lr) * 32 + lk];
        #pragma unroll
        for (int j = 0; j < 2; ++j) bfv[j] = *(const bf16x8*)&Bs[cur][(wc + j * 16 + lr) * 32 + lk];
        #pragma unroll
        for (int i = 0; i < 4; ++i)
            #pragma unroll
            for (int j = 0; j < 2; ++j)
                acc[i][j] = __builtin_amdgcn_mfma_f32_16x16x32_bf16(af[i], bfv[j], acc[i][j], 0, 0, 0);
    }
    float bias[2];
    #pragma unroll
    for (int j = 0; j < 2; ++j) bias[j] = b3[n0 + wc + j * 16 + lr];
    #pragma unroll
    for (int i = 0; i < 4; ++i)
        #pragma unroll
        for (int r = 0; r < 4; ++r) {
            int m = m0 + wr + i * 16 + (l >> 4) * 4 + r;
            if (m < 14400) {
                int bl = m / 900, pos = m - bl * 900;
                size_t ob = ((size_t)(f0 + bl) * 1024 + pos) * 256;
                #pragma unroll
                for (int j = 0; j < 2; ++j)
                    feat[ob + n0 + wc + j * 16 + lr] = f2bf(fmaxf(acc[i][j][r] + bias[j], 0.f));
            }
        }
}

// ======================= l2norm: wave per row, rows 900..1023 zeroed =========
__global__ __launch_bounds__(256) void k_l2norm(unsigned short* __restrict__ feat) {
    const int t = threadIdx.x, wv = t >> 6, ln = t & 63;
    const int R = blockIdx.x * 4 + wv;             // 32768 rows, grid 8192
    const int pos = R & 1023;
    ushort4* fp4 = (ushort4*)(feat + (size_t)R * 256);
    if (pos >= 900) { fp4[ln] = make_ushort4(0, 0, 0, 0); return; }
    ushort4 u = fp4[ln];
    float x0 = bf2f(u.x), x1 = bf2f(u.y), x2 = bf2f(u.z), x3 = bf2f(u.w);
    float s = x0 * x0 + x1 * x1 + x2 * x2 + x3 * x3;
    #pragma unroll
    for (int m = 1; m < 64; m <<= 1) s += __shfl_xor(s, m);
    const float inv = 1.f / sqrtf(s + EPSF);
    u.x = f2bf(x0 * inv); u.y = f2bf(x1 * inv);
    u.z = f2bf(x2 * inv); u.w = f2bf(x3 * inv);
    fp4[ln] = u;
}

// ======================= corr MFMA: per-b 1024x1024 padded, 128-tile =========
__global__ __launch_bounds__(256) void k_corr(
        const unsigned short* __restrict__ feat, unsigned short* __restrict__ corr) {
    __shared__ __align__(16) unsigned short As[4][128 * 32];
    __shared__ __align__(16) unsigned short Bs[4][128 * 32];
    const int t = threadIdx.x, w = t >> 6, l = t & 63;
    const int id0 = blockIdx.x;                            // 1024
    const int sw = (id0 & 7) * 128 + (id0 >> 3);           // bijective XCD swizzle
    const int b = sw >> 6, rem = sw & 63;
    const int p0 = (rem >> 3) * 128, q0 = (rem & 7) * 128;
    const int ko = (l & 3) * 8;
    const unsigned short* fA = feat + (size_t)b * 1024 * 256;
    const unsigned short* fB = feat + (size_t)(16 + b) * 1024 * 256;
    size_t aga[2], bga[2];
    #pragma unroll
    for (int i = 0; i < 2; ++i) {
        int r = (w * 2 + i) * 16 + (l >> 2);
        aga[i] = (size_t)(p0 + r) * 256 + ko;
        bga[i] = (size_t)(q0 + r) * 256 + ko;
    }
    const int wr = (w >> 1) * 64, wc = (w & 1) * 64, lr = l & 15, lk = (l >> 4) * 8;
    f32x4 acc[4][4] = {};
    auto stage = [&](int s) {
        int buf = s & 3;
        #pragma unroll
        for (int i = 0; i < 2; ++i) {
            gl16(fA + aga[i] + s * 32, &As[buf][(w * 2 + i) * 512]);
            gl16(fB + bga[i] + s * 32, &Bs[buf][(w * 2 + i) * 512]);
        }
    };
    stage(0); stage(1); stage(2);
    for (int s = 0; s < 8; ++s) {
        if (s + 2 < 8)      { PIPE_WAIT(8) }
        else if (s + 1 < 8) { PIPE_WAIT(4) }
        else                { PIPE_WAIT(0) }
        if (s + 3 < 8) stage(s + 3);
        const int cur = s & 3;
        bf16x8 af[4], bfv[4];
        #pragma unroll
        for (int i = 0; i < 4; ++i) af[i] = *(const bf16x8*)&As[cur][(wr + i * 16 + lr) * 32 + lk];
        #pragma unroll
        for (int j = 0; j < 4; ++j) bfv[j] = *(const bf16x8*)&Bs[cur][(wc + j * 16 + lr) * 32 + lk];
        #pragma unroll
        for (int i = 0; i < 4; ++i)
            #pragma unroll
            for (int j = 0; j < 4; ++j)
                acc[i][j] = __builtin_amdgcn_mfma_f32_16x16x32_bf16(af[i], bfv[j], acc[i][j], 0, 0, 0);
    }
    unsigned short* cb = corr + (size_t)b * 960 * 960;
    #pragma unroll
    for (int i = 0; i < 4; ++i)
        #pragma unroll
        for (int r = 0; r < 4; ++r) {
            int row = p0 + wr + i * 16 + (l >> 4) * 4 + r;
            if (row < 960) {
                #pragma unroll
                for (int j = 0; j < 4; ++j) {
                    int col = q0 + wc + j * 16 + lr;
                    if (col < 960)
                        cb[(size_t)row * 960 + col] = f2bf(fmaxf(acc[i][j][r], 0.f));
                }
            }
        }
}

// ======================= corr L2 norm: one wave per row ======================
__global__ __launch_bounds__(256) void k_corrnorm(unsigned short* __restrict__ corr) {
    const int t = threadIdx.x, wv = t >> 6, ln = t & 63;
    const int row = blockIdx.x * 4 + wv;       // 14400 rows, grid 3600
    const int b = row / 900, p = row - b * 900;
    ushort4* cp4 = (ushort4*)(corr + ((size_t)b * 960 + p) * 960);
    float x[16];
    float s = 0.f;
    #pragma unroll
    for (int i = 0; i < 4; ++i) {
        const int idx = ln + 64 * i;
        float v0 = 0.f, v1 = 0.f, v2 = 0.f, v3 = 0.f;
        if (idx < 225) {
            ushort4 u = cp4[idx];
            v0 = fmaxf(bf2f(u.x), 0.f); v1 = fmaxf(bf2f(u.y), 0.f);
            v2 = fmaxf(bf2f(u.z), 0.f); v3 = fmaxf(bf2f(u.w), 0.f);
        }
        x[i * 4 + 0] = v0; x[i * 4 + 1] = v1; x[i * 4 + 2] = v2; x[i * 4 + 3] = v3;
        s += v0 * v0 + v1 * v1 + v2 * v2 + v3 * v3;
    }
    #pragma unroll
    for (int m = 1; m < 64; m <<= 1) s += __shfl_xor(s, m);
    const float sc = 1.f / sqrtf(s + EPSF);
    #pragma unroll
    for (int i = 0; i < 4; ++i) {
        const int idx = ln + 64 * i;
        if (idx < 225) {
            ushort4 u;
            u.x = f2bf(x[i * 4 + 0] * sc); u.y = f2bf(x[i * 4 + 1] * sc);
            u.z = f2bf(x[i * 4 + 2] * sc); u.w = f2bf(x[i * 4 + 3] * sc);
            cp4[idx] = u;
        }
    }
}

// ======================= cw1 MFMA v7 (best measured: 101 us, 1030 TF) ========
// M=9216 N=128; 8 waves of 128x64; BK=32/phase; 4-seg LDS ring; T2 swizzle;
// ONE barrier per phase; counted vmcnt 10/5/0; setprio. grid 252 = 18mt x 14ks.
__global__ __launch_bounds__(512, 1) void k_cw1(
        const unsigned short* __restrict__ corr, const unsigned short* __restrict__ Wt,
        unsigned short* __restrict__ part) {
    __shared__ __align__(16) unsigned short As[4 * 512 * 32];   // 128 KB
    __shared__ __align__(16) unsigned short Bs[4 * 128 * 32];   // 32 KB
    const int t = threadIdx.x, w = t >> 6, l = t & 63;
    const int bid = blockIdx.x;
    const int mt = bid % 18, ks = bid / 18;
    const int m0 = mt * 512;
    // staging: row = t>>2, phys chunk = t&3; fetch global chunk = (t&3)^((row>>1)&3)
    const int kswz = ((t & 3) ^ ((t >> 3) & 3)) * 8;
    size_t aga[4];
    #pragma unroll
    for (int i = 0; i < 4; ++i) {
        int r = i * 128 + (t >> 2);
        int m = m0 + r;
        int b = m / 576, rem = m - b * 576, oy = rem / 24, ox = rem - oy * 24;
        aga[i] = (size_t)(b * 960 + oy * 30 + ox) * 960 + kswz;
    }
    const size_t bga = (size_t)(t >> 2) * 45472 + kswz;
    // q-major K schedule: 1421 steps of 32; ks<7 get 102, else 101
    const int sbase = ks * 101 + min(ks, 7);
    const int nt = 101 + (ks < 7 ? 1 : 0);
    const int wm = (w >> 1) * 128, wn = (w & 1) * 64;
    const int lr = l & 15, cI = l >> 4;
    const int rsw = (cI ^ ((lr >> 1) & 3)) * 8;     // swizzled read chunk (elems)
    f32x4 acc[8][4] = {};
    auto stage = [&](int sidx) {
        const int seg = sidx & 3;
        const int s = sbase + sidx;
        const int qi = s / 49, sq = s - qi * 49;
        const int ky = sq / 7, kx = sq - ky * 7;
        const int aoff = (ky * 30 + kx) * 960 + qi * 32;
        const int boff = sq * 928 + qi * 32;
        #pragma unroll
        for (int i = 0; i < 4; ++i)
            gl16(corr + aga[i] + aoff, &As[seg * 16384 + i * 4096 + w * 512]);
        gl16(Wt + bga + boff, &Bs[seg * 4096 + w * 512]);
    };
    stage(0); stage(1); stage(2);
    for (int s = 0; s < nt; ++s) {
        if (s + 2 < nt) {
            asm volatile("s_waitcnt vmcnt(10)" ::: "memory");
        } else if (s + 1 < nt) {
            asm volatile("s_waitcnt vmcnt(5)" ::: "memory");
        } else {
            asm volatile("s_waitcnt vmcnt(0)" ::: "memory");
        }
        __builtin_amdgcn_sched_barrier(0);
        __builtin_amdgcn_s_barrier();
        __builtin_amdgcn_sched_barrier(0);
        const int seg = s & 3;
        bf16x8 af[8], bfv[4];
        #pragma unroll
        for (int i = 0; i < 8; ++i)
            af[i] = *(const bf16x8*)&As[seg * 16384 + (wm + i * 16 + lr) * 32 + rsw];
        #pragma unroll
        for (int j = 0; j < 4; ++j)
            bfv[j] = *(const bf16x8*)&Bs[seg * 4096 + (wn + j * 16 + lr) * 32 + rsw];
        if (s + 3 < nt) stage(s + 3);
        asm volatile("s_waitcnt lgkmcnt(0)" ::: "memory");
        __builtin_amdgcn_sched_barrier(0);
        __builtin_amdgcn_s_setprio(1);
        #pragma unroll
        for (int i = 0; i < 8; ++i)
            #pragma unroll
            for (int j = 0; j < 4; ++j)
                acc[i][j] = __builtin_amdgcn_mfma_f32_16x16x32_bf16(af[i], bfv[j], acc[i][j], 0, 0, 0);
        __builtin_amdgcn_s_setprio(0);
        __builtin_amdgcn_sched_barrier(0);
        // no trailing barrier: single rendezvous per phase
    }
    unsigned short* pb = part + ((size_t)ks * 9216 + m0) * 128;
    #pragma unroll
    for (int i = 0; i < 8; ++i)
        #pragma unroll
        for (int r = 0; r < 4; ++r) {
            int row = wm + i * 16 + (l >> 4) * 4 + r;
            #pragma unroll
            for (int j = 0; j < 4; ++j)
                pb[(size_t)row * 128 + wn + j * 16 + lr] = f2h(acc[i][j][r]);
        }
}

// ======================= reduce 14 fp16 partials + bias + relu + BN -> bf16 ==
__global__ __launch_bounds__(256) void k_r1fin(
        const unsigned short* __restrict__ part, const float* __restrict__ cb1,
        const float* __restrict__ g1, const float* __restrict__ be1,
        const float* __restrict__ m1, const float* __restrict__ v1,
        unsigned short* __restrict__ r1) {
    const int idx = blockIdx.x * 256 + threadIdx.x;        // grid 1152
    const size_t base = (size_t)idx * 4;
    const size_t N = 9216 * 128;
    float s0 = 0.f, s1 = 0.f, s2 = 0.f, s3 = 0.f;
    #pragma unroll
    for (int i = 0; i < 14; ++i) {
        ushort4 u = *(const ushort4*)(part + i * N + base);
        s0 += h2f(u.x); s1 += h2f(u.y); s2 += h2f(u.z); s3 += h2f(u.w);
    }
    const int co = (int)(base & 127);
    float r[4] = {s0, s1, s2, s3};
    ushort4 o;
    unsigned short* op = (unsigned short*)&o;
    #pragma unroll
    for (int j = 0; j < 4; ++j) {
        int c = co + j;
        float x = fmaxf(r[j] + cb1[c], 0.f);
        x = (x - m1[c]) * (g1[c] / sqrtf(v1[c] + BN_EPSF)) + be1[c];
        op[j] = f2bf(x);
    }
    *(ushort4*)(r1 + base) = o;
}

// ======================= cw2 MFMA: M=6400 N=64 K=3200, K-split 4, 4-buf ======
__global__ __launch_bounds__(256) void k_cw2(
        const unsigned short* __restrict__ r1, const unsigned short* __restrict__ Wt2,
        float* __restrict__ partC) {
    __shared__ __align__(16) unsigned short As[4][64 * 32];
    __shared__ __align__(16) unsigned short Bs[4][64 * 32];
    const int t = threadIdx.x, w = t >> 6, l = t & 63;
    const int bid = blockIdx.x;                            // 400
    const int mtb = bid % 100, ks = bid / 100;
    const int m0 = mtb * 64;
    const int sbase = ks * 25;
    const int ko = (l & 3) * 8;
    const int wi = w & 1;
    size_t ga[2];
    #pragma unroll
    for (int i = 0; i < 2; ++i) {
        int r = (wi * 2 + i) * 16 + (l >> 2);
        if (w < 2) {
            int m = m0 + r;
            int b = m / 400, rem = m - b * 400, oy = rem / 20, ox = rem - oy * 20;
            ga[i] = (size_t)((b * 24 + oy) * 24 + ox) * 128 + ko;
        } else {
            ga[i] = (size_t)r * 3200 + ko;
        }
    }
    const int wr = (w >> 1) * 32, wc = (w & 1) * 32, lr = l & 15, lk = (l >> 4) * 8;
    f32x4 acc[2][2] = {};
    auto stage = [&](int sidx) {
        int buf = sidx & 3;
        int s = sbase + sidx;
        int kyx = s >> 2, h = s & 3;
        int ky = kyx / 5, kx = kyx - ky * 5;
        int aoff = (ky * 24 + kx) * 128 + h * 32;
        int boff = s * 32;
        #pragma unroll
        for (int i = 0; i < 2; ++i) {
            unsigned short* dst = (w < 2) ? &As[buf][(wi * 2 + i) * 512]
                                          : &Bs[buf][(wi * 2 + i) * 512];
            const unsigned short* src = (w < 2) ? r1 + ga[i] + aoff : Wt2 + ga[i] + boff;
            gl16(src, dst);
        }
    };
    stage(0); stage(1); stage(2);
    for (int s = 0; s < 25; ++s) {
        if (s + 2 < 25)      { PIPE_WAIT(4) }
        else if (s + 1 < 25) { PIPE_WAIT(2) }
        else                 { PIPE_WAIT(0) }
        if (s + 3 < 25) stage(s + 3);
        const int cur = s & 3;
        bf16x8 af[2], bfv[2];
        #pragma unroll
        for (int i = 0; i < 2; ++i) af[i] = *(const bf16x8*)&As[cur][(wr + i * 16 + lr) * 32 + lk];
        #pragma unroll
        for (int j = 0; j < 2; ++j) bfv[j] = *(const bf16x8*)&Bs[cur][(wc + j * 16 + lr) * 32 + lk];
        #pragma unroll
        for (int i = 0; i < 2; ++i)
            #pragma unroll
            for (int j = 0; j < 2; ++j)
                acc[i][j] = __builtin_amdgcn_mfma_f32_16x16x32_bf16(af[i], bfv[j], acc[i][j], 0, 0, 0);
    }
    float* pc = partC + (size_t)ks * 409600;
    #pragma unroll
    for (int i = 0; i < 2; ++i)
        #pragma unroll
        for (int r = 0; r < 4; ++r) {
            int m = m0 + wr + i * 16 + (l >> 4) * 4 + r;
            #pragma unroll
            for (int j = 0; j < 2; ++j)
                pc[(size_t)m * 64 + wc + j * 16 + lr] = acc[i][j][r];
        }
}

// ======================= dense: fold cw2 finalize + matvec, K-split 16 =======
__global__ __launch_bounds__(256) void k_dense(
        const float* __restrict__ partC, const float* __restrict__ cb2,
        const float* __restrict__ g2, const float* __restrict__ be2,
        const float* __restrict__ m2, const float* __restrict__ v2,
        const float* __restrict__ dw, float* __restrict__ partD) {
    const int b = blockIdx.x, kb = blockIdx.y, t = threadIdx.x;  // (16,16)
    const int co = t & 63;
    const float sc2 = g2[co] / sqrtf(v2[co] + BN_EPSF);
    const float sh2 = be2[co] - m2[co] * sc2;
    const float bb = cb2[co];
    float s[18] = {};
    for (int k = t; k < 1600; k += 256) {
        const int kk = kb * 1600 + k;
        const size_t pi = (size_t)(b * 400 + (kk >> 6)) * 64 + co;
        float p = partC[pi] + partC[pi + 409600] + partC[pi + 819200] + partC[pi + 1228800];
        p = fmaxf(p + bb, 0.f) * sc2 + sh2;
        const float* dr = dw + (size_t)kk * 18;
        #pragma unroll
        for (int j = 0; j < 18; ++j) s[j] = fmaf(p, dr[j], s[j]);
    }
    #pragma unroll
    for (int j = 0; j < 18; ++j)
        #pragma unroll
        for (int m = 1; m < 64; m <<= 1) s[j] += __shfl_xor(s[j], m);
    __shared__ float red[4][18];
    if ((t & 63) == 0) {
        #pragma unroll
        for (int j = 0; j < 18; ++j) red[t >> 6][j] = s[j];
    }
    __syncthreads();
    if (t < 18) partD[(b * 16 + kb) * 18 + t] = red[0][t] + red[1][t] + red[2][t] + red[3][t];
}
__global__ __launch_bounds__(288) void k_dfin(
        const float* __restrict__ partD, const float* __restrict__ db,
        float* __restrict__ out) {
    const int i = threadIdx.x;                 // 288
    const int b = i / 18, j = i - b * 18;
    float s = db[j];
    #pragma unroll
    for (int k = 0; k < 16; ++k) s += partD[(b * 16 + k) * 18 + j];
    out[i] = s;
}

extern "C" void kernel_launch(void* const* d_in, const int* in_sizes, int n_in,
                              void* d_out, int out_size, void* d_ws, size_t ws_size,
                              hipStream_t stream) {
    const float* imgA = (const float*)d_in[0];
    const float* imgB = (const float*)d_in[1];
    const float* w1  = (const float*)d_in[2];
    const float* b1  = (const float*)d_in[3];
    const float* w2  = (const float*)d_in[4];
    const float* b2  = (const float*)d_in[5];
    const float* w3  = (const float*)d_in[6];
    const float* b3  = (const float*)d_in[7];
    const float* cw1 = (const float*)d_in[8];
    const float* cb1 = (const float*)d_in[9];
    const float* g1  = (const float*)d_in[10];
    const float* be1 = (const float*)d_in[11];
    const float* m1  = (const float*)d_in[12];
    const float* v1  = (const float*)d_in[13];
    const float* cw2 = (const float*)d_in[14];
    const float* cb2 = (const float*)d_in[15];
    const float* g2  = (const float*)d_in[16];
    const float* be2 = (const float*)d_in[17];
    const float* m2  = (const float*)d_in[18];
    const float* v2  = (const float*)d_in[19];
    const float* dw  = (const float*)d_in[20];
    const float* db  = (const float*)d_in[21];

    // ws layout (bytes), max end = 77,150,208:
    //  persistent : Wt@62,740,480 (11.64MB, written by k_wx up front)
    //  conv phase : c1@0 (30.0MB) c2@29,984,768 (15.2MB) w2t@45,225,984
    //               w3t@45,373,440  feat@45,963,264 (16.8MB, [32][1024][256])
    //  corr phase : corr@0 (29.5MB, c1 dead)
    //  cw1 phase  : part@29,491,200 (33.0MB fp16 x14; feat/c2/w2t/w3t dead;
    //               ends 62,521,344 < Wt)
    //  tail       : r1@74,381,312 (2.36MB)  Wt2@76,740,608 (0.41MB)
    //               partC@0 (6.55MB, corr dead)  partD@6,553,600 (18.4KB)
    char* ws = (char*)d_ws;
    unsigned short* c1   = (unsigned short*)(ws + 0);
    unsigned short* c2   = (unsigned short*)(ws + 29984768);
    unsigned short* w2t  = (unsigned short*)(ws + 45225984);
    unsigned short* w3t  = (unsigned short*)(ws + 45373440);
    unsigned short* feat = (unsigned short*)(ws + 45963264);
    unsigned short* Wt   = (unsigned short*)(ws + 62740480);
    unsigned short* corr = (unsigned short*)(ws + 0);
    unsigned short* part = (unsigned short*)(ws + 29491200);
    unsigned short* r1   = (unsigned short*)(ws + 74381312);
    unsigned short* Wt2  = (unsigned short*)(ws + 76740608);
    float*          partC= (float*)(ws + 0);
    float*          partD= (float*)(ws + 6553600);

    k_wx<<<dim3(3661), 256, 0, stream>>>(w2, w3, cw2, cw1, w2t, w3t, Wt2, Wt);

    for (int chunk = 0; chunk < 2; ++chunk) {
        const float* img = chunk ? imgB : imgA;
        const int f0 = chunk * 16;
        k_conv1<<<dim3(15, 30, 16), 256, 0, stream>>>(img, w1, b1, c1);
        k_conv2<<<dim3(450),        256, 0, stream>>>(c1, w2t, b2, c2);
        k_conv3<<<dim3(113, 4),     256, 0, stream>>>(c2, w3t, b3, feat, f0);
    }
    k_l2norm  <<<dim3(8192),  256, 0, stream>>>(feat);
    k_corr    <<<dim3(1024),  256, 0, stream>>>(feat, corr);
    k_corrnorm<<<dim3(3600),  256, 0, stream>>>(corr);
    k_cw1     <<<dim3(252),   512, 0, stream>>>(corr, Wt, part);
    k_r1fin   <<<dim3(1152),  256, 0, stream>>>(part, cb1, g1, be1, m1, v1, r1);
    k_cw2     <<<dim3(400),   256, 0, stream>>>(r1, Wt2, partC);
    k_dense   <<<dim3(16, 16),256, 0, stream>>>(partC, cb2, g2, be2, m2, v2, dw, partD);
    k_dfin    <<<dim3(1),     288, 0, stream>>>(partD, db, (float*)d_out);
}